// Round 6
// baseline (561.812 us; speedup 1.0000x reference)
//
#include <hip/hip_runtime.h>
#include <math.h>

typedef __bf16 bf16;
typedef __bf16 bf16x8 __attribute__((ext_vector_type(8)));
typedef float f32x4 __attribute__((ext_vector_type(4)));
typedef float f32x16 __attribute__((ext_vector_type(16)));
typedef unsigned int u32x4 __attribute__((ext_vector_type(4)));

__device__ __forceinline__ void load_lds16(const void* g, void* l) {
    __builtin_amdgcn_global_load_lds(
        (const __attribute__((address_space(1))) unsigned int*)g,
        (__attribute__((address_space(3))) unsigned int*)l, 16, 0, 0);
}

__device__ __forceinline__ float bf_lo(unsigned u) { return __uint_as_float(u << 16); }
__device__ __forceinline__ float bf_hi(unsigned u) { return __uint_as_float(u & 0xffff0000u); }

// ---------------------------------------------------------------------------
// prep_w2: W2 [cout][ci][tap] f32 -> B-fragment buffer for mfma_32x32x16_bf16.
// frag f = s*2 + nt  (s = K-slice 0..17: tap=s>>1, ci_base=(s&1)*16; nt = cout half)
// ---------------------------------------------------------------------------
__global__ void prep_w2(const float* __restrict__ W2, bf16* __restrict__ w2r) {
    int e = blockIdx.x * 256 + threadIdx.x;     // 0..18431
    int j  = e & 7;
    int l  = (e >> 3) & 63;
    int f  = e >> 9;
    int s  = f >> 1;
    int nt = f & 1;
    int tap  = s >> 1;
    int ci   = (s & 1) * 16 + (l >> 5) * 8 + j;
    int cout = nt * 32 + (l & 31);
    w2r[e] = (bf16)W2[cout * 288 + ci * 9 + tap];
}

// ---------------------------------------------------------------------------
// prep_wl1t: Wl1 f32 [12544][128] -> bf16 [128][12544] with permuted K:
// wl1t[n][k'] where k' = site*64 + cout  <->  Wl1 row k = cout*196 + site.
// ---------------------------------------------------------------------------
__global__ void prep_wl1t(const float* __restrict__ Wl1, bf16* __restrict__ wl1t) {
    __shared__ float tile[32 * 129];
    const int t  = threadIdx.x;
    const int s  = blockIdx.x;      // site 0..195
    const int cg = blockIdx.y;      // cout half
    for (int e = t; e < 4096; e += 256) {
        int cl = e >> 7, n = e & 127;
        tile[cl * 129 + n] = Wl1[((long)(cg * 32 + cl) * 196 + s) * 128 + n];
    }
    __syncthreads();
    for (int e = t; e < 4096; e += 256) {
        int n = e >> 5, cl = e & 31;
        wl1t[(long)n * 12544 + s * 64 + cg * 32 + cl] = (bf16)tile[cl * 129 + n];
    }
}

// ---------------------------------------------------------------------------
// conv_fused: conv1(masked,relu,VALU) + conv2(masked,relu,MFMA 32x32x16) + pool.
// One block = one image half (14 conv rows; h1 tile 16x30x32 ci, swizzled).
// W2 B-frags in 72 VGPRs/wave. xs staged as bf16 (LDS 31.9KB -> 4 blocks/CU).
// conv2: dual accumulator chains (ci-half split) + one-tap-ahead A prefetch.
// launch_bounds(256,4): VGPR cap 128 (audit: ~115 peak + 32 AGPR, no spill).
// ---------------------------------------------------------------------------
__global__ __launch_bounds__(256, 4)
void conv_fused(const float* __restrict__ x, const float* __restrict__ W1,
                const float* __restrict__ b1, const bf16* __restrict__ w2r,
                const float* __restrict__ b2, bf16* __restrict__ pooled)
{
    __shared__ __attribute__((aligned(16))) bf16 h1s[16 * 30 * 32];  // swizzled
    __shared__ __attribute__((aligned(16))) bf16 xs[18 * 32];        // bf16 tile

    const int t    = threadIdx.x;
    const int lane = t & 63;
    const int wv   = t >> 6;
    const int img  = blockIdx.x >> 1;
    const int hb   = blockIdx.x & 1;        // image half
    const int nt   = wv & 1;                // cout half this wave computes
    const int wp   = wv >> 1;               // Mt parity this wave computes

    const float* xi = x + img * 784;

    // W2 B-frags -> 72 VGPRs early (L2-resident; latency hides behind staging)
    bf16x8 breg[18];
    {
        const bf16x8* wp2 = (const bf16x8*)w2r;
        #pragma unroll
        for (int s = 0; s < 18; s++)
            breg[s] = wp2[(2 * s + nt) * 64 + lane];
    }

    // conv1 weights into regs
    const int ci = t & 31;
    const int g  = t >> 5;          // g<7 active in conv1
    float w1r[9];
    #pragma unroll
    for (int k = 0; k < 9; k++) w1r[k] = W1[ci * 9 + k];
    const float b1r = b1[ci];

    // stage x tile (bf16): xs[j][c] = x[hb*14-2+j][c-1], 18 rows
    for (int e = t; e < 18 * 32; e += 256) {
        int j  = e >> 5;
        int c  = e & 31;
        int xr = hb * 14 - 2 + j;
        int xc = c - 1;
        float v = 0.f;
        if (xr >= 0 && xr < 28 && xc >= 0 && xc < 28) v = xi[xr * 28 + xc];
        xs[e] = (bf16)v;
    }
    // zero halo cols 0 and 29 (swizzle permutes within-row dwords only)
    for (int e = t; e < 512; e += 256) {
        int d   = e & 15;
        int idx = e >> 4;           // 0..31
        int r   = idx >> 1;
        int p   = r * 30 + (idx & 1) * 29;
        ((unsigned int*)h1s)[p * 16 + d] = 0u;
    }
    __syncthreads();

    // ---- conv1: register sliding window, 4-col strip per thread; always-write
    if (g < 7) {
        const unsigned int* xw = (const unsigned int*)xs;
        const int w0 = g * 2;                   // word base within row (c0 = g*4)
        float win[3][6];
        #pragma unroll
        for (int j0 = 0; j0 < 2; j0++) {
            unsigned a = xw[j0 * 16 + w0], b = xw[j0 * 16 + w0 + 1],
                     c = xw[j0 * 16 + w0 + 2];
            win[j0][0] = bf_lo(a); win[j0][1] = bf_hi(a);
            win[j0][2] = bf_lo(b); win[j0][3] = bf_hi(b);
            win[j0][4] = bf_lo(c); win[j0][5] = bf_hi(c);
        }
        #pragma unroll
        for (int r = 0; r < 16; r++) {
            {
                float* d = win[(r + 2) % 3];
                unsigned a = xw[(r + 2) * 16 + w0], b = xw[(r + 2) * 16 + w0 + 1],
                         c = xw[(r + 2) * 16 + w0 + 2];
                d[0] = bf_lo(a); d[1] = bf_hi(a);
                d[2] = bf_lo(b); d[3] = bf_hi(b);
                d[4] = bf_lo(c); d[5] = bf_hi(c);
            }
            int ghr = hb * 14 - 1 + r;          // global conv row
            bool rv = (ghr >= 0) && (ghr <= 27);
            const float* a0 = win[r % 3];
            const float* a1 = win[(r + 1) % 3];
            const float* a2 = win[(r + 2) % 3];
            #pragma unroll
            for (int j = 0; j < 4; j++) {
                float s = b1r
                    + a0[j] * w1r[0] + a0[j + 1] * w1r[1] + a0[j + 2] * w1r[2]
                    + a1[j] * w1r[3] + a1[j + 1] * w1r[4] + a1[j + 2] * w1r[5]
                    + a2[j] * w1r[6] + a2[j + 1] * w1r[7] + a2[j + 2] * w1r[8];
                float cm = a1[j + 1];
                float o  = (rv && cm != 0.f && s > 0.f) ? s : 0.f;
                int p = r * 30 + g * 4 + j + 1;
                h1s[(p * 32 + ci) ^ ((p & 6) << 2)] = (bf16)o;
            }
        }
    }
    __syncthreads();    // h1s ready

    // ---- conv2: Mt loop over 13 tiles of 32 M-rows (98 pooled sites/half)
    const int ml31  = lane & 31;
    const int half  = lane >> 5;
    const int cib   = half * 8;
    const int coutl = nt * 32 + ml31;
    const float bias = b2[coutl];

    int q  = ml31 & 3;
    int pj = wp * 8 + (ml31 >> 2);
    int pi = 0;
    if (pj >= 14) { pj -= 14; pi = 1; }
    int epj = wp * 8 + half;
    int epi = 0;

    bf16* pout = pooled + (long)img * 12544 + hb * 98 * 64 + coutl;
    const unsigned short* xsu = (const unsigned short*)xs;

    for (int Mt = wp; Mt < 13; Mt += 2) {
        int row = 2 * pi + (q >> 1);
        if (row > 13) row = 13;                 // Mt=12 tail clamp (stores guarded)
        int pb = row * 30 + 2 * pj + (q & 1);

        // dual accumulator chains: accA = ci 0..15 side, accB = ci 16..31 side
        f32x16 accA = {}, accB = {};
        // prefetch tap 0
        int p0  = pb;
        int sw0 = (p0 & 6) << 2;
        bf16x8 a0 = *(const bf16x8*)&h1s[((p0 * 32 + cib) ^ sw0)];
        bf16x8 a1 = *(const bf16x8*)&h1s[((p0 * 32 + 16 + cib) ^ sw0)];
        #pragma unroll
        for (int kt = 0; kt < 9; kt++) {
            bf16x8 na0, na1;
            if (kt < 8) {
                const int dp = ((kt + 1) / 3) * 30 + ((kt + 1) % 3);
                int p  = pb + dp;
                int sw = (p & 6) << 2;
                na0 = *(const bf16x8*)&h1s[((p * 32 + cib) ^ sw)];
                na1 = *(const bf16x8*)&h1s[((p * 32 + 16 + cib) ^ sw)];
            }
            accA = __builtin_amdgcn_mfma_f32_32x32x16_bf16(a0, breg[2 * kt],     accA, 0, 0, 0);
            accB = __builtin_amdgcn_mfma_f32_32x32x16_bf16(a1, breg[2 * kt + 1], accB, 0, 0, 0);
            a0 = na0; a1 = na1;
        }

        // epilogue: +bias, mask, relu, 2x2 maxpool, direct global store
        int e_pi = epi, e_pj = epj;
        int slg  = 8 * Mt + half;
        #pragma unroll
        for (int gg = 0; gg < 4; gg++) {
            if (slg < 98) {
                float pmax = 0.f;
                #pragma unroll
                for (int qi = 0; qi < 4; qi++) {
                    float v = accA[gg * 4 + qi] + accB[gg * 4 + qi] + bias;
                    unsigned short cmu = xsu[(2 * e_pi + (qi >> 1) + 2) * 32
                                             + 2 * e_pj + (qi & 1) + 1];
                    v = ((cmu & 0x7fff) != 0 && v > 0.f) ? v : 0.f;
                    pmax = v > pmax ? v : pmax;
                }
                pout[slg * 64] = (bf16)pmax;
            }
            slg += 2;
            e_pj += 2; if (e_pj >= 14) { e_pj -= 14; e_pi += 1; }
        }

        pj += 2; if (pj >= 14) { pj -= 14; pi += 1; }
        pi += 1;
        epj += 2; if (epj >= 14) { epj -= 14; epi += 1; }
        epi += 1;
    }
}

// ---------------------------------------------------------------------------
// fc1: bf16 MFMA split-K GEMM, ping-pong double-buffered global_load_lds.
// part[ks][m][n] = A[m, ks*1568:+1568] * Wl1.  A = pooled bf16 [4096][12544];
// B = wl1t bf16 [128][12544] (same permuted K order). grid (128 Mb x 8 Ks).
// ---------------------------------------------------------------------------
__global__ __launch_bounds__(256, 4)
void fc1(const bf16* __restrict__ pooled, const bf16* __restrict__ wl1t,
         float* __restrict__ part)
{
    __shared__ __attribute__((aligned(16))) bf16 As[2][32 * 32];
    __shared__ __attribute__((aligned(16))) bf16 Bs[2][128 * 32];

    const int t    = threadIdx.x;
    const int lane = t & 63;
    const int wv   = t >> 6;
    const int ml   = lane & 15;
    const int kg   = lane >> 4;
    const int wm   = wv & 1;
    const int wn   = wv >> 1;
    const int m0   = blockIdx.x * 32;
    const int ks   = blockIdx.y;
    const int k0   = ks * 1568;

    const int achunk = wv * 64 + lane;          // 0..127 (wv<2)
    const int arow   = achunk >> 2;
    const int aqs    = (achunk & 3) ^ ((arow >> 1) & 3);
    const bf16* asrc = pooled + (long)(m0 + arow) * 12544 + aqs * 8;

    int bn[2], bofs[2];
    const bf16* bsrc[2];
    #pragma unroll
    for (int u = 0; u < 2; u++) {
        int c   = wv * 128 + u * 64 + lane;
        bn[u]   = c >> 2;
        int qs  = (c & 3) ^ ((bn[u] >> 1) & 3);
        bsrc[u] = wl1t + (long)bn[u] * 12544 + qs * 8;
        bofs[u] = (wv * 128 + u * 64) * 8;
    }

    const int am  = wm * 16 + ml;
    const int aoff = (am * 32 + kg * 8) ^ ((am & 6) << 2);
    int boff[4];
    #pragma unroll
    for (int j = 0; j < 4; j++) {
        int n = wn * 64 + j * 16 + ml;
        boff[j] = (n * 32 + kg * 8) ^ ((n & 6) << 2);
    }

    f32x4 acc[4];
    {
        f32x4 z = {0.f, 0.f, 0.f, 0.f};
        #pragma unroll
        for (int j = 0; j < 4; j++) acc[j] = z;
    }

    if (wv < 2) load_lds16(asrc + k0, &As[0][wv * 512]);
    #pragma unroll
    for (int u = 0; u < 2; u++) load_lds16(bsrc[u] + k0, &Bs[0][bofs[u]]);

    for (int kt = 0; kt < 49; kt++) {
        __syncthreads();
        const int cur = kt & 1;
        if (kt < 48) {
            const int kb = k0 + (kt + 1) * 32;
            const int nb = cur ^ 1;
            if (wv < 2) load_lds16(asrc + kb, &As[nb][wv * 512]);
            #pragma unroll
            for (int u = 0; u < 2; u++) load_lds16(bsrc[u] + kb, &Bs[nb][bofs[u]]);
        }
        bf16x8 af = *(const bf16x8*)&As[cur][aoff];
        #pragma unroll
        for (int j = 0; j < 4; j++) {
            bf16x8 bf = *(const bf16x8*)&Bs[cur][boff[j]];
            acc[j] = __builtin_amdgcn_mfma_f32_16x16x32_bf16(af, bf, acc[j], 0, 0, 0);
        }
    }

    float* pp = part + ((long)ks * 4096 + m0 + wm * 16) * 128 + wn * 64;
    #pragma unroll
    for (int j = 0; j < 4; j++)
        #pragma unroll
        for (int r = 0; r < 4; r++)
            pp[(kg * 4 + r) * 128 + j * 16 + ml] = acc[j][r];
}

// ---------------------------------------------------------------------------
// fc2_lsm: one wave per image; 8-way split-K reduce + FC2 + log_softmax.
// ---------------------------------------------------------------------------
__global__ __launch_bounds__(256)
void fc2_lsm(const float* __restrict__ part, const float* __restrict__ bl1,
             const float* __restrict__ Wl2, const float* __restrict__ bl2,
             float* __restrict__ out)
{
    const int wv   = threadIdx.x >> 6;
    const int lane = threadIdx.x & 63;
    const int img  = blockIdx.x * 4 + wv;
    const float* pb = part + (long)img * 128;

    float ac[10];
    #pragma unroll
    for (int c = 0; c < 10; c++) ac[c] = 0.f;

    #pragma unroll
    for (int u = 0; u < 2; u++) {
        int n = lane + 64 * u;
        float s = bl1[n];
        #pragma unroll
        for (int k = 0; k < 8; k++) s += pb[(long)k * 4096 * 128 + n];
        float h = s > 0.f ? s : 0.f;
        #pragma unroll
        for (int c = 0; c < 10; c++) ac[c] += h * Wl2[n * 10 + c];
    }
    #pragma unroll
    for (int o = 32; o > 0; o >>= 1)
        #pragma unroll
        for (int c = 0; c < 10; c++) ac[c] += __shfl_down(ac[c], o, 64);

    if (lane == 0) {
        float lg[10], mx = -1e30f;
        #pragma unroll
        for (int c = 0; c < 10; c++) {
            lg[c] = ac[c] + bl2[c];
            mx = lg[c] > mx ? lg[c] : mx;
        }
        float se = 0.f;
        #pragma unroll
        for (int c = 0; c < 10; c++) se += __expf(lg[c] - mx);
        float ls = __logf(se);
        #pragma unroll
        for (int c = 0; c < 10; c++) out[img * 10 + c] = lg[c] - mx - ls;
    }
}

// ---------------------------------------------------------------------------
extern "C" void kernel_launch(void* const* d_in, const int* in_sizes, int n_in,
                              void* d_out, int out_size, void* d_ws, size_t ws_size,
                              hipStream_t stream) {
    const float* x   = (const float*)d_in[0];
    const float* W1  = (const float*)d_in[1];
    const float* b1  = (const float*)d_in[2];
    const float* W2  = (const float*)d_in[3];
    const float* b2  = (const float*)d_in[4];
    const float* Wl1 = (const float*)d_in[5];
    const float* bl1 = (const float*)d_in[6];
    const float* Wl2 = (const float*)d_in[7];
    const float* bl2 = (const float*)d_in[8];
    float* out = (float*)d_out;

    char* ws = (char*)d_ws;
    bf16*  w2r    = (bf16*)ws;                                   // 36,864 B
    bf16*  wl1t   = (bf16*)(ws + 65536);                         // 3,211,264 B
    bf16*  pooled = (bf16*)(ws + 65536 + 4194304);               // 102,760,448 B
    float* part   = (float*)(ws + 65536 + 4194304 + 102760448);  // 16,777,216 B

    prep_w2   <<<72,             256, 0, stream>>>(W2, w2r);
    prep_wl1t <<<dim3(196, 2),   256, 0, stream>>>(Wl1, wl1t);
    conv_fused<<<8192,           256, 0, stream>>>(x, W1, b1, w2r, b2, pooled);
    fc1       <<<dim3(128, 8),   256, 0, stream>>>(pooled, wl1t, part);
    fc2_lsm   <<<1024,           256, 0, stream>>>(part, bl1, Wl2, bl2, out);
}

// Round 7
// 346.821 us; speedup vs baseline: 1.6199x; 1.6199x over previous
//
#include <hip/hip_runtime.h>
#include <math.h>

typedef __bf16 bf16;
typedef __bf16 bf16x8 __attribute__((ext_vector_type(8)));
typedef float f32x4 __attribute__((ext_vector_type(4)));
typedef float f32x16 __attribute__((ext_vector_type(16)));
typedef unsigned int u32x4 __attribute__((ext_vector_type(4)));

__device__ __forceinline__ void load_lds16(const void* g, void* l) {
    __builtin_amdgcn_global_load_lds(
        (const __attribute__((address_space(1))) unsigned int*)g,
        (__attribute__((address_space(3))) unsigned int*)l, 16, 0, 0);
}

__device__ __forceinline__ float bf_lo(unsigned u) { return __uint_as_float(u << 16); }
__device__ __forceinline__ float bf_hi(unsigned u) { return __uint_as_float(u & 0xffff0000u); }

// ---------------------------------------------------------------------------
// prep_w2: W2 [cout][ci][tap] f32 -> B-fragment buffer for mfma_32x32x16_bf16.
// frag f = s*2 + nt  (s = K-slice 0..17: tap=s>>1, ci_base=(s&1)*16; nt = cout half)
// ---------------------------------------------------------------------------
__global__ void prep_w2(const float* __restrict__ W2, bf16* __restrict__ w2r) {
    int e = blockIdx.x * 256 + threadIdx.x;     // 0..18431
    int j  = e & 7;
    int l  = (e >> 3) & 63;
    int f  = e >> 9;
    int s  = f >> 1;
    int nt = f & 1;
    int tap  = s >> 1;
    int ci   = (s & 1) * 16 + (l >> 5) * 8 + j;
    int cout = nt * 32 + (l & 31);
    w2r[e] = (bf16)W2[cout * 288 + ci * 9 + tap];
}

// ---------------------------------------------------------------------------
// prep_wl1t: Wl1 f32 [12544][128] -> bf16 [128][12544] with permuted K:
// wl1t[n][k'] where k' = site*64 + cout  <->  Wl1 row k = cout*196 + site.
// ---------------------------------------------------------------------------
__global__ void prep_wl1t(const float* __restrict__ Wl1, bf16* __restrict__ wl1t) {
    __shared__ float tile[32 * 129];
    const int t  = threadIdx.x;
    const int s  = blockIdx.x;      // site 0..195
    const int cg = blockIdx.y;      // cout half
    for (int e = t; e < 4096; e += 256) {
        int cl = e >> 7, n = e & 127;
        tile[cl * 129 + n] = Wl1[((long)(cg * 32 + cl) * 196 + s) * 128 + n];
    }
    __syncthreads();
    for (int e = t; e < 4096; e += 256) {
        int n = e >> 5, cl = e & 31;
        wl1t[(long)n * 12544 + s * 64 + cg * 32 + cl] = (bf16)tile[cl * 129 + n];
    }
}

// ---------------------------------------------------------------------------
// conv_fused: conv1(masked,relu,VALU) + conv2(masked,relu,MFMA 32x32x16) + pool.
// One block = one image half (14 conv rows; h1 tile 16x30x32 ci, swizzled).
// W2 B-frags in 72 VGPRs/wave. xs staged as bf16.
// conv2: dual accumulator chains (ci-half split) + one-tap-ahead A prefetch.
// __launch_bounds__(256,3) REQUIRED: reg plan = 72 breg + 32 acc + conv1
// window ~= 150 regs. (256,4) caps arch+acc at 128 total -> spills breg ->
// 1.3 GB scratch traffic (R3 AND R6 both hit this). DO NOT raise to 4.
// ---------------------------------------------------------------------------
__global__ __launch_bounds__(256, 3)
void conv_fused(const float* __restrict__ x, const float* __restrict__ W1,
                const float* __restrict__ b1, const bf16* __restrict__ w2r,
                const float* __restrict__ b2, bf16* __restrict__ pooled)
{
    __shared__ __attribute__((aligned(16))) bf16 h1s[16 * 30 * 32];  // swizzled
    __shared__ __attribute__((aligned(16))) bf16 xs[18 * 32];        // bf16 tile

    const int t    = threadIdx.x;
    const int lane = t & 63;
    const int wv   = t >> 6;
    const int img  = blockIdx.x >> 1;
    const int hb   = blockIdx.x & 1;        // image half
    const int nt   = wv & 1;                // cout half this wave computes
    const int wp   = wv >> 1;               // Mt parity this wave computes

    const float* xi = x + img * 784;

    // W2 B-frags -> 72 VGPRs early (L2-resident; latency hides behind staging)
    bf16x8 breg[18];
    {
        const bf16x8* wp2 = (const bf16x8*)w2r;
        #pragma unroll
        for (int s = 0; s < 18; s++)
            breg[s] = wp2[(2 * s + nt) * 64 + lane];
    }

    // conv1 weights into regs
    const int ci = t & 31;
    const int g  = t >> 5;          // g<7 active in conv1
    float w1r[9];
    #pragma unroll
    for (int k = 0; k < 9; k++) w1r[k] = W1[ci * 9 + k];
    const float b1r = b1[ci];

    // stage x tile (bf16): xs[j][c] = x[hb*14-2+j][c-1], 18 rows
    for (int e = t; e < 18 * 32; e += 256) {
        int j  = e >> 5;
        int c  = e & 31;
        int xr = hb * 14 - 2 + j;
        int xc = c - 1;
        float v = 0.f;
        if (xr >= 0 && xr < 28 && xc >= 0 && xc < 28) v = xi[xr * 28 + xc];
        xs[e] = (bf16)v;
    }
    // zero halo cols 0 and 29 (swizzle permutes within-row dwords only)
    for (int e = t; e < 512; e += 256) {
        int d   = e & 15;
        int idx = e >> 4;           // 0..31
        int r   = idx >> 1;
        int p   = r * 30 + (idx & 1) * 29;
        ((unsigned int*)h1s)[p * 16 + d] = 0u;
    }
    __syncthreads();

    // ---- conv1: register sliding window, 4-col strip per thread; always-write
    if (g < 7) {
        const unsigned int* xw = (const unsigned int*)xs;
        const int w0 = g * 2;                   // word base within row (c0 = g*4)
        float win[3][6];
        #pragma unroll
        for (int j0 = 0; j0 < 2; j0++) {
            unsigned a = xw[j0 * 16 + w0], b = xw[j0 * 16 + w0 + 1],
                     c = xw[j0 * 16 + w0 + 2];
            win[j0][0] = bf_lo(a); win[j0][1] = bf_hi(a);
            win[j0][2] = bf_lo(b); win[j0][3] = bf_hi(b);
            win[j0][4] = bf_lo(c); win[j0][5] = bf_hi(c);
        }
        #pragma unroll
        for (int r = 0; r < 16; r++) {
            {
                float* d = win[(r + 2) % 3];
                unsigned a = xw[(r + 2) * 16 + w0], b = xw[(r + 2) * 16 + w0 + 1],
                         c = xw[(r + 2) * 16 + w0 + 2];
                d[0] = bf_lo(a); d[1] = bf_hi(a);
                d[2] = bf_lo(b); d[3] = bf_hi(b);
                d[4] = bf_lo(c); d[5] = bf_hi(c);
            }
            int ghr = hb * 14 - 1 + r;          // global conv row
            bool rv = (ghr >= 0) && (ghr <= 27);
            const float* a0 = win[r % 3];
            const float* a1 = win[(r + 1) % 3];
            const float* a2 = win[(r + 2) % 3];
            #pragma unroll
            for (int j = 0; j < 4; j++) {
                float s = b1r
                    + a0[j] * w1r[0] + a0[j + 1] * w1r[1] + a0[j + 2] * w1r[2]
                    + a1[j] * w1r[3] + a1[j + 1] * w1r[4] + a1[j + 2] * w1r[5]
                    + a2[j] * w1r[6] + a2[j + 1] * w1r[7] + a2[j + 2] * w1r[8];
                float cm = a1[j + 1];
                float o  = (rv && cm != 0.f && s > 0.f) ? s : 0.f;
                int p = r * 30 + g * 4 + j + 1;
                h1s[(p * 32 + ci) ^ ((p & 6) << 2)] = (bf16)o;
            }
        }
    }
    __syncthreads();    // h1s ready

    // ---- conv2: Mt loop over 13 tiles of 32 M-rows (98 pooled sites/half)
    const int ml31  = lane & 31;
    const int half  = lane >> 5;
    const int cib   = half * 8;
    const int coutl = nt * 32 + ml31;
    const float bias = b2[coutl];

    int q  = ml31 & 3;
    int pj = wp * 8 + (ml31 >> 2);
    int pi = 0;
    if (pj >= 14) { pj -= 14; pi = 1; }
    int epj = wp * 8 + half;
    int epi = 0;

    bf16* pout = pooled + (long)img * 12544 + hb * 98 * 64 + coutl;
    const unsigned short* xsu = (const unsigned short*)xs;

    for (int Mt = wp; Mt < 13; Mt += 2) {
        int row = 2 * pi + (q >> 1);
        if (row > 13) row = 13;                 // Mt=12 tail clamp (stores guarded)
        int pb = row * 30 + 2 * pj + (q & 1);

        // dual accumulator chains: accA = ci 0..15 side, accB = ci 16..31 side
        f32x16 accA = {}, accB = {};
        // prefetch tap 0
        int p0  = pb;
        int sw0 = (p0 & 6) << 2;
        bf16x8 a0 = *(const bf16x8*)&h1s[((p0 * 32 + cib) ^ sw0)];
        bf16x8 a1 = *(const bf16x8*)&h1s[((p0 * 32 + 16 + cib) ^ sw0)];
        #pragma unroll
        for (int kt = 0; kt < 9; kt++) {
            bf16x8 na0, na1;
            if (kt < 8) {
                const int dp = ((kt + 1) / 3) * 30 + ((kt + 1) % 3);
                int p  = pb + dp;
                int sw = (p & 6) << 2;
                na0 = *(const bf16x8*)&h1s[((p * 32 + cib) ^ sw)];
                na1 = *(const bf16x8*)&h1s[((p * 32 + 16 + cib) ^ sw)];
            }
            accA = __builtin_amdgcn_mfma_f32_32x32x16_bf16(a0, breg[2 * kt],     accA, 0, 0, 0);
            accB = __builtin_amdgcn_mfma_f32_32x32x16_bf16(a1, breg[2 * kt + 1], accB, 0, 0, 0);
            a0 = na0; a1 = na1;
        }

        // epilogue: +bias, mask, relu, 2x2 maxpool, direct global store
        int e_pi = epi, e_pj = epj;
        int slg  = 8 * Mt + half;
        #pragma unroll
        for (int gg = 0; gg < 4; gg++) {
            if (slg < 98) {
                float pmax = 0.f;
                #pragma unroll
                for (int qi = 0; qi < 4; qi++) {
                    float v = accA[gg * 4 + qi] + accB[gg * 4 + qi] + bias;
                    unsigned short cmu = xsu[(2 * e_pi + (qi >> 1) + 2) * 32
                                             + 2 * e_pj + (qi & 1) + 1];
                    v = ((cmu & 0x7fff) != 0 && v > 0.f) ? v : 0.f;
                    pmax = v > pmax ? v : pmax;
                }
                pout[slg * 64] = (bf16)pmax;
            }
            slg += 2;
            e_pj += 2; if (e_pj >= 14) { e_pj -= 14; e_pi += 1; }
        }

        pj += 2; if (pj >= 14) { pj -= 14; pi += 1; }
        pi += 1;
        epj += 2; if (epj >= 14) { epj -= 14; epi += 1; }
        epi += 1;
    }
}

// ---------------------------------------------------------------------------
// fc1: bf16 MFMA split-K GEMM, ping-pong double-buffered global_load_lds.
// part[ks][m][n] = A[m, ks*1568:+1568] * Wl1.  A = pooled bf16 [4096][12544];
// B = wl1t bf16 [128][12544] (same permuted K order). grid (128 Mb x 8 Ks).
// ---------------------------------------------------------------------------
__global__ __launch_bounds__(256, 4)
void fc1(const bf16* __restrict__ pooled, const bf16* __restrict__ wl1t,
         float* __restrict__ part)
{
    __shared__ __attribute__((aligned(16))) bf16 As[2][32 * 32];
    __shared__ __attribute__((aligned(16))) bf16 Bs[2][128 * 32];

    const int t    = threadIdx.x;
    const int lane = t & 63;
    const int wv   = t >> 6;
    const int ml   = lane & 15;
    const int kg   = lane >> 4;
    const int wm   = wv & 1;
    const int wn   = wv >> 1;
    const int m0   = blockIdx.x * 32;
    const int ks   = blockIdx.y;
    const int k0   = ks * 1568;

    const int achunk = wv * 64 + lane;          // 0..127 (wv<2)
    const int arow   = achunk >> 2;
    const int aqs    = (achunk & 3) ^ ((arow >> 1) & 3);
    const bf16* asrc = pooled + (long)(m0 + arow) * 12544 + aqs * 8;

    int bn[2], bofs[2];
    const bf16* bsrc[2];
    #pragma unroll
    for (int u = 0; u < 2; u++) {
        int c   = wv * 128 + u * 64 + lane;
        bn[u]   = c >> 2;
        int qs  = (c & 3) ^ ((bn[u] >> 1) & 3);
        bsrc[u] = wl1t + (long)bn[u] * 12544 + qs * 8;
        bofs[u] = (wv * 128 + u * 64) * 8;
    }

    const int am  = wm * 16 + ml;
    const int aoff = (am * 32 + kg * 8) ^ ((am & 6) << 2);
    int boff[4];
    #pragma unroll
    for (int j = 0; j < 4; j++) {
        int n = wn * 64 + j * 16 + ml;
        boff[j] = (n * 32 + kg * 8) ^ ((n & 6) << 2);
    }

    f32x4 acc[4];
    {
        f32x4 z = {0.f, 0.f, 0.f, 0.f};
        #pragma unroll
        for (int j = 0; j < 4; j++) acc[j] = z;
    }

    if (wv < 2) load_lds16(asrc + k0, &As[0][wv * 512]);
    #pragma unroll
    for (int u = 0; u < 2; u++) load_lds16(bsrc[u] + k0, &Bs[0][bofs[u]]);

    for (int kt = 0; kt < 49; kt++) {
        __syncthreads();
        const int cur = kt & 1;
        if (kt < 48) {
            const int kb = k0 + (kt + 1) * 32;
            const int nb = cur ^ 1;
            if (wv < 2) load_lds16(asrc + kb, &As[nb][wv * 512]);
            #pragma unroll
            for (int u = 0; u < 2; u++) load_lds16(bsrc[u] + kb, &Bs[nb][bofs[u]]);
        }
        bf16x8 af = *(const bf16x8*)&As[cur][aoff];
        #pragma unroll
        for (int j = 0; j < 4; j++) {
            bf16x8 bf = *(const bf16x8*)&Bs[cur][boff[j]];
            acc[j] = __builtin_amdgcn_mfma_f32_16x16x32_bf16(af, bf, acc[j], 0, 0, 0);
        }
    }

    float* pp = part + ((long)ks * 4096 + m0 + wm * 16) * 128 + wn * 64;
    #pragma unroll
    for (int j = 0; j < 4; j++)
        #pragma unroll
        for (int r = 0; r < 4; r++)
            pp[(kg * 4 + r) * 128 + j * 16 + ml] = acc[j][r];
}

// ---------------------------------------------------------------------------
// fc2_lsm: one wave per image; 8-way split-K reduce + FC2 + log_softmax.
// ---------------------------------------------------------------------------
__global__ __launch_bounds__(256)
void fc2_lsm(const float* __restrict__ part, const float* __restrict__ bl1,
             const float* __restrict__ Wl2, const float* __restrict__ bl2,
             float* __restrict__ out)
{
    const int wv   = threadIdx.x >> 6;
    const int lane = threadIdx.x & 63;
    const int img  = blockIdx.x * 4 + wv;
    const float* pb = part + (long)img * 128;

    float ac[10];
    #pragma unroll
    for (int c = 0; c < 10; c++) ac[c] = 0.f;

    #pragma unroll
    for (int u = 0; u < 2; u++) {
        int n = lane + 64 * u;
        float s = bl1[n];
        #pragma unroll
        for (int k = 0; k < 8; k++) s += pb[(long)k * 4096 * 128 + n];
        float h = s > 0.f ? s : 0.f;
        #pragma unroll
        for (int c = 0; c < 10; c++) ac[c] += h * Wl2[n * 10 + c];
    }
    #pragma unroll
    for (int o = 32; o > 0; o >>= 1)
        #pragma unroll
        for (int c = 0; c < 10; c++) ac[c] += __shfl_down(ac[c], o, 64);

    if (lane == 0) {
        float lg[10], mx = -1e30f;
        #pragma unroll
        for (int c = 0; c < 10; c++) {
            lg[c] = ac[c] + bl2[c];
            mx = lg[c] > mx ? lg[c] : mx;
        }
        float se = 0.f;
        #pragma unroll
        for (int c = 0; c < 10; c++) se += __expf(lg[c] - mx);
        float ls = __logf(se);
        #pragma unroll
        for (int c = 0; c < 10; c++) out[img * 10 + c] = lg[c] - mx - ls;
    }
}

// ---------------------------------------------------------------------------
extern "C" void kernel_launch(void* const* d_in, const int* in_sizes, int n_in,
                              void* d_out, int out_size, void* d_ws, size_t ws_size,
                              hipStream_t stream) {
    const float* x   = (const float*)d_in[0];
    const float* W1  = (const float*)d_in[1];
    const float* b1  = (const float*)d_in[2];
    const float* W2  = (const float*)d_in[3];
    const float* b2  = (const float*)d_in[4];
    const float* Wl1 = (const float*)d_in[5];
    const float* bl1 = (const float*)d_in[6];
    const float* Wl2 = (const float*)d_in[7];
    const float* bl2 = (const float*)d_in[8];
    float* out = (float*)d_out;

    char* ws = (char*)d_ws;
    bf16*  w2r    = (bf16*)ws;                                   // 36,864 B
    bf16*  wl1t   = (bf16*)(ws + 65536);                         // 3,211,264 B
    bf16*  pooled = (bf16*)(ws + 65536 + 4194304);               // 102,760,448 B
    float* part   = (float*)(ws + 65536 + 4194304 + 102760448);  // 16,777,216 B

    prep_w2   <<<72,             256, 0, stream>>>(W2, w2r);
    prep_wl1t <<<dim3(196, 2),   256, 0, stream>>>(Wl1, wl1t);
    conv_fused<<<8192,           256, 0, stream>>>(x, W1, b1, w2r, b2, pooled);
    fc1       <<<dim3(128, 8),   256, 0, stream>>>(pooled, wl1t, part);
    fc2_lsm   <<<1024,           256, 0, stream>>>(part, bl1, Wl2, bl2, out);
}

// Round 9
// 278.973 us; speedup vs baseline: 2.0139x; 1.2432x over previous
//
#include <hip/hip_runtime.h>
#include <math.h>

typedef __bf16 bf16;
typedef __bf16 bf16x8 __attribute__((ext_vector_type(8)));
typedef float f32x4 __attribute__((ext_vector_type(4)));
typedef float f32x16 __attribute__((ext_vector_type(16)));
typedef unsigned int u32x4 __attribute__((ext_vector_type(4)));

__device__ __forceinline__ void load_lds16(const void* g, void* l) {
    __builtin_amdgcn_global_load_lds(
        (const __attribute__((address_space(1))) unsigned int*)g,
        (__attribute__((address_space(3))) unsigned int*)l, 16, 0, 0);
}

// ---------------------------------------------------------------------------
// prep_w2: W2 [cout][ci][tap] f32 -> B-frag buffer for mfma_32x32x16 (conv2),
// PLUS W1 [32][9] f32 -> B-frag buffer w1f for conv1 (K=16, taps 9..15 = 0).
// ---------------------------------------------------------------------------
__global__ void prep_w2(const float* __restrict__ W2, bf16* __restrict__ w2r,
                        const float* __restrict__ W1, bf16* __restrict__ w1f) {
    int e = blockIdx.x * 256 + threadIdx.x;
    if (e < 18432) {
        int j  = e & 7;
        int l  = (e >> 3) & 63;
        int f  = e >> 9;
        int s  = f >> 1;
        int nt = f & 1;
        int tap  = s >> 1;
        int ci   = (s & 1) * 16 + (l >> 5) * 8 + j;
        int cout = nt * 32 + (l & 31);
        w2r[e] = (bf16)W2[cout * 288 + ci * 9 + tap];
    } else {
        int e2 = e - 18432;
        if (e2 < 512) {
            int j = e2 & 7;
            int l = e2 >> 3;
            int k = (l >> 5) * 8 + j;       // tap index (K)
            int n = l & 31;                 // cout
            w1f[e2] = (k < 9) ? (bf16)W1[n * 9 + k] : (bf16)0.f;
        }
    }
}

// ---------------------------------------------------------------------------
// prep_wl1t: Wl1 f32 [12544][128] -> bf16 [128][12544] with permuted K:
// wl1t[n][k'] where k' = site*64 + cout  <->  Wl1 row k = cout*196 + site.
// ---------------------------------------------------------------------------
__global__ void prep_wl1t(const float* __restrict__ Wl1, bf16* __restrict__ wl1t) {
    __shared__ float tile[32 * 129];
    const int t  = threadIdx.x;
    const int s  = blockIdx.x;      // site 0..195
    const int cg = blockIdx.y;      // cout half
    for (int e = t; e < 4096; e += 256) {
        int cl = e >> 7, n = e & 127;
        tile[cl * 129 + n] = Wl1[((long)(cg * 32 + cl) * 196 + s) * 128 + n];
    }
    __syncthreads();
    for (int e = t; e < 4096; e += 256) {
        int n = e >> 5, cl = e & 31;
        wl1t[(long)n * 12544 + s * 64 + cg * 32 + cl] = (bf16)tile[cl * 129 + n];
    }
}

// ---------------------------------------------------------------------------
// conv_fused: BOTH convs on the MFMA pipe.
//  phase1: im2col x -> Aim[480 pos][16 taps] bf16 + masks mrow/mneg (f32)
//          !! every LDS fill > 256 elements MUST be a strided loop — R8's
//          `if (t < 392)` left mneg[256..391] poisoned (0xAA) -> absmax 1.6.
//  phase2: conv1 = MFMA 32x32x16 (M=480 pos, N=32 cout, K=16) + mask/relu
//          scatter into swizzled h1s
//  phase3: conv2 = MFMA 32x32x16 per Mt, epilogue = mneg-add + max + relu,
//          direct global store pooled[img][site*64+cout]
// __launch_bounds__(256,3) REQUIRED: breg 72 + acc 32 + misc > 128-reg cap of
// (256,4) -> spills (R3, R6: 1.3 GB scratch). DO NOT raise to 4.
// ---------------------------------------------------------------------------
__global__ __launch_bounds__(256, 3)
void conv_fused(const float* __restrict__ x, const float* __restrict__ b1,
                const bf16* __restrict__ w2r, const bf16* __restrict__ w1f,
                const float* __restrict__ b2, bf16* __restrict__ pooled)
{
    __shared__ __attribute__((aligned(16))) bf16  h1s[16 * 30 * 32];  // 30720 B
    __shared__ __attribute__((aligned(16))) bf16  Aim[480 * 16];      // 15360 B
    __shared__ __attribute__((aligned(16))) float xs[18 * 32];        //  2304 B
    __shared__ __attribute__((aligned(16))) float mrow[480];          //  1920 B
    __shared__ __attribute__((aligned(16))) float mneg[98 * 4];       //  1568 B

    const int t    = threadIdx.x;
    const int lane = t & 63;
    const int wv   = t >> 6;
    const int img  = blockIdx.x >> 1;
    const int hb   = blockIdx.x & 1;        // image half
    const int nt   = wv & 1;                // conv2 cout half
    const int wp   = wv >> 1;               // conv2 Mt parity
    const int ml31 = lane & 31;
    const int lg   = lane >> 5;

    const float* xi = x + img * 784;

    // global loads early (L2-resident; latency hides behind staging)
    bf16x8 breg[18];
    {
        const bf16x8* wp2 = (const bf16x8*)w2r;
        #pragma unroll
        for (int s = 0; s < 18; s++)
            breg[s] = wp2[(2 * s + nt) * 64 + lane];
    }
    const bf16x8 w1frag = *(const bf16x8*)&w1f[lane * 8];
    const float  b1r    = b1[ml31];               // conv1 bias (cout = lane&31)
    const float  bias2  = b2[nt * 32 + ml31];     // conv2 bias

    // stage x tile f32: xs[j][c] = x[hb*14-2+j][c-1], 18 rows
    for (int e = t; e < 18 * 32; e += 256) {
        int j  = e >> 5;
        int c  = e & 31;
        int xr = hb * 14 - 2 + j;
        int xc = c - 1;
        float v = 0.f;
        if (xr >= 0 && xr < 28 && xc >= 0 && xc < 28) v = xi[xr * 28 + xc];
        xs[e] = v;
    }
    __syncthreads();

    // ---- phase 1: im2col + masks
    #pragma unroll
    for (int pp = 0; pp < 2; pp++) {
        int p = t + pp * 256;
        if (p < 480) {
            int r = p / 30, c = p - r * 30;
            const float* xb = &xs[r * 32 + c - 1];  // c-1 may be -1: masked pos
            float v0 = xb[0],  v1 = xb[1],  v2 = xb[2];
            float v3 = xb[32], v4 = xb[33], v5 = xb[34];
            float v6 = xb[64], v7 = xb[65], v8 = xb[66];
            bf16x8 t0;
            t0[0] = (bf16)v0; t0[1] = (bf16)v1; t0[2] = (bf16)v2;
            t0[3] = (bf16)v3; t0[4] = (bf16)v4; t0[5] = (bf16)v5;
            t0[6] = (bf16)v6; t0[7] = (bf16)v7;
            bf16x8 t1;
            #pragma unroll
            for (int j = 0; j < 8; j++) t1[j] = (bf16)0.f;
            t1[0] = (bf16)v8;
            *(bf16x8*)&Aim[p * 16]     = t0;
            *(bf16x8*)&Aim[p * 16 + 8] = t1;
            // mask: center x (v4) nonzero AND col in [1,28]
            mrow[p] = (c >= 1 && c <= 28 && v4 != 0.f) ? 1.f : 0.f;
        }
    }
    // mneg: 392 entries > 256 threads -> MUST be a strided loop (R8 bug)
    for (int e = t; e < 392; e += 256) {
        int s   = e >> 2, q = e & 3;
        int spi = s / 14, spj = s - spi * 14;
        float cv = xs[(2 * spi + (q >> 1) + 2) * 32 + 2 * spj + (q & 1) + 1];
        mneg[e] = (cv != 0.f) ? 0.f : -1e30f;
    }
    __syncthreads();

    // ---- phase 2: conv1 via MFMA 32x32x16 (15 M-tiles split across waves)
    for (int Mt = wv; Mt < 15; Mt += 4) {
        int m = Mt * 32 + ml31;
        bf16x8 af = *(const bf16x8*)&Aim[m * 16 + lg * 8];
        f32x16 acc;
        #pragma unroll
        for (int e = 0; e < 16; e++) acc[e] = b1r;   // bias folded into init
        acc = __builtin_amdgcn_mfma_f32_32x32x16_bf16(af, w1frag, acc, 0, 0, 0);
        #pragma unroll
        for (int run = 0; run < 4; run++) {
            int p0 = Mt * 32 + run * 8 + 4 * lg;     // C/D row base (4 consec)
            f32x4 mk = *(const f32x4*)&mrow[p0];
            #pragma unroll
            for (int j = 0; j < 4; j++) {
                float s = acc[run * 4 + j];
                float o = (mk[j] != 0.f) ? fmaxf(s, 0.f) : 0.f;  // select: NaN-safe
                int p = p0 + j;
                h1s[(p * 32 + ml31) ^ ((p & 6) << 2)] = (bf16)o;
            }
        }
    }
    __syncthreads();    // h1s ready

    // ---- phase 3: conv2 Mt loop (13 tiles of 32 M-rows, 98 pooled sites)
    const int half = lg;
    const int cib  = half * 8;

    int q  = ml31 & 3;
    int pj = wp * 8 + (ml31 >> 2);
    int pi = 0;
    if (pj >= 14) { pj -= 14; pi = 1; }

    bf16* pout = pooled + (long)img * 12544 + hb * 98 * 64 + nt * 32 + ml31;

    for (int Mt = wp; Mt < 13; Mt += 2) {
        int row = 2 * pi + (q >> 1);
        if (row > 13) row = 13;                 // Mt=12 tail clamp (stores guarded)
        int pb = row * 30 + 2 * pj + (q & 1);

        // dual chains; conv2 bias folded into accA init
        f32x16 accA, accB = {};
        #pragma unroll
        for (int e = 0; e < 16; e++) accA[e] = bias2;

        int p0  = pb;
        int sw0 = (p0 & 6) << 2;
        bf16x8 a0 = *(const bf16x8*)&h1s[((p0 * 32 + cib) ^ sw0)];
        bf16x8 a1 = *(const bf16x8*)&h1s[((p0 * 32 + 16 + cib) ^ sw0)];
        #pragma unroll
        for (int kt = 0; kt < 9; kt++) {
            bf16x8 na0, na1;
            if (kt < 8) {
                const int dp = ((kt + 1) / 3) * 30 + ((kt + 1) % 3);
                int p  = pb + dp;
                int sw = (p & 6) << 2;
                na0 = *(const bf16x8*)&h1s[((p * 32 + cib) ^ sw)];
                na1 = *(const bf16x8*)&h1s[((p * 32 + 16 + cib) ^ sw)];
            }
            accA = __builtin_amdgcn_mfma_f32_32x32x16_bf16(a0, breg[2 * kt],     accA, 0, 0, 0);
            accB = __builtin_amdgcn_mfma_f32_32x32x16_bf16(a1, breg[2 * kt + 1], accB, 0, 0, 0);
            a0 = na0; a1 = na1;
        }

        // epilogue: fold chains, add mneg (0 / -1e30), max over quad, relu
        int slg = 8 * Mt + half;
        #pragma unroll
        for (int gg = 0; gg < 4; gg++) {
            if (slg < 98) {
                f32x4 mn = *(const f32x4*)&mneg[slg * 4];
                float v0 = accA[gg * 4 + 0] + accB[gg * 4 + 0] + mn[0];
                float v1 = accA[gg * 4 + 1] + accB[gg * 4 + 1] + mn[1];
                float v2 = accA[gg * 4 + 2] + accB[gg * 4 + 2] + mn[2];
                float v3 = accA[gg * 4 + 3] + accB[gg * 4 + 3] + mn[3];
                float pm = fmaxf(fmaxf(v0, v1), fmaxf(v2, v3));
                pout[slg * 64] = (bf16)fmaxf(pm, 0.f);
            }
            slg += 2;
        }

        pj += 2; if (pj >= 14) { pj -= 14; pi += 1; }
        pi += 1;
    }
}

// ---------------------------------------------------------------------------
// fc1: bf16 MFMA split-K GEMM, ping-pong double-buffered global_load_lds.
// part[ks][m][n] = A[m, ks*1568:+1568] * Wl1.  A = pooled bf16 [4096][12544];
// B = wl1t bf16 [128][12544] (same permuted K order). grid (128 Mb x 8 Ks).
// ---------------------------------------------------------------------------
__global__ __launch_bounds__(256, 4)
void fc1(const bf16* __restrict__ pooled, const bf16* __restrict__ wl1t,
         float* __restrict__ part)
{
    __shared__ __attribute__((aligned(16))) bf16 As[2][32 * 32];
    __shared__ __attribute__((aligned(16))) bf16 Bs[2][128 * 32];

    const int t    = threadIdx.x;
    const int lane = t & 63;
    const int wv   = t >> 6;
    const int ml   = lane & 15;
    const int kg   = lane >> 4;
    const int wm   = wv & 1;
    const int wn   = wv >> 1;
    const int m0   = blockIdx.x * 32;
    const int ks   = blockIdx.y;
    const int k0   = ks * 1568;

    const int achunk = wv * 64 + lane;          // 0..127 (wv<2)
    const int arow   = achunk >> 2;
    const int aqs    = (achunk & 3) ^ ((arow >> 1) & 3);
    const bf16* asrc = pooled + (long)(m0 + arow) * 12544 + aqs * 8;

    int bn[2], bofs[2];
    const bf16* bsrc[2];
    #pragma unroll
    for (int u = 0; u < 2; u++) {
        int c   = wv * 128 + u * 64 + lane;
        bn[u]   = c >> 2;
        int qs  = (c & 3) ^ ((bn[u] >> 1) & 3);
        bsrc[u] = wl1t + (long)bn[u] * 12544 + qs * 8;
        bofs[u] = (wv * 128 + u * 64) * 8;
    }

    const int am  = wm * 16 + ml;
    const int aoff = (am * 32 + kg * 8) ^ ((am & 6) << 2);
    int boff[4];
    #pragma unroll
    for (int j = 0; j < 4; j++) {
        int n = wn * 64 + j * 16 + ml;
        boff[j] = (n * 32 + kg * 8) ^ ((n & 6) << 2);
    }

    f32x4 acc[4];
    {
        f32x4 z = {0.f, 0.f, 0.f, 0.f};
        #pragma unroll
        for (int j = 0; j < 4; j++) acc[j] = z;
    }

    if (wv < 2) load_lds16(asrc + k0, &As[0][wv * 512]);
    #pragma unroll
    for (int u = 0; u < 2; u++) load_lds16(bsrc[u] + k0, &Bs[0][bofs[u]]);

    for (int kt = 0; kt < 49; kt++) {
        __syncthreads();
        const int cur = kt & 1;
        if (kt < 48) {
            const int kb = k0 + (kt + 1) * 32;
            const int nb = cur ^ 1;
            if (wv < 2) load_lds16(asrc + kb, &As[nb][wv * 512]);
            #pragma unroll
            for (int u = 0; u < 2; u++) load_lds16(bsrc[u] + kb, &Bs[nb][bofs[u]]);
        }
        bf16x8 af = *(const bf16x8*)&As[cur][aoff];
        #pragma unroll
        for (int j = 0; j < 4; j++) {
            bf16x8 bf = *(const bf16x8*)&Bs[cur][boff[j]];
            acc[j] = __builtin_amdgcn_mfma_f32_16x16x32_bf16(af, bf, acc[j], 0, 0, 0);
        }
    }

    float* pp = part + ((long)ks * 4096 + m0 + wm * 16) * 128 + wn * 64;
    #pragma unroll
    for (int j = 0; j < 4; j++)
        #pragma unroll
        for (int r = 0; r < 4; r++)
            pp[(kg * 4 + r) * 128 + j * 16 + ml] = acc[j][r];
}

// ---------------------------------------------------------------------------
// fc2_lsm: one wave per image; 8-way split-K reduce + FC2 + log_softmax.
// ---------------------------------------------------------------------------
__global__ __launch_bounds__(256)
void fc2_lsm(const float* __restrict__ part, const float* __restrict__ bl1,
             const float* __restrict__ Wl2, const float* __restrict__ bl2,
             float* __restrict__ out)
{
    const int wv   = threadIdx.x >> 6;
    const int lane = threadIdx.x & 63;
    const int img  = blockIdx.x * 4 + wv;
    const float* pb = part + (long)img * 128;

    float ac[10];
    #pragma unroll
    for (int c = 0; c < 10; c++) ac[c] = 0.f;

    #pragma unroll
    for (int u = 0; u < 2; u++) {
        int n = lane + 64 * u;
        float s = bl1[n];
        #pragma unroll
        for (int k = 0; k < 8; k++) s += pb[(long)k * 4096 * 128 + n];
        float h = s > 0.f ? s : 0.f;
        #pragma unroll
        for (int c = 0; c < 10; c++) ac[c] += h * Wl2[n * 10 + c];
    }
    #pragma unroll
    for (int o = 32; o > 0; o >>= 1)
        #pragma unroll
        for (int c = 0; c < 10; c++) ac[c] += __shfl_down(ac[c], o, 64);

    if (lane == 0) {
        float lg[10], mx = -1e30f;
        #pragma unroll
        for (int c = 0; c < 10; c++) {
            lg[c] = ac[c] + bl2[c];
            mx = lg[c] > mx ? lg[c] : mx;
        }
        float se = 0.f;
        #pragma unroll
        for (int c = 0; c < 10; c++) se += __expf(lg[c] - mx);
        float ls = __logf(se);
        #pragma unroll
        for (int c = 0; c < 10; c++) out[img * 10 + c] = lg[c] - mx - ls;
    }
}

// ---------------------------------------------------------------------------
extern "C" void kernel_launch(void* const* d_in, const int* in_sizes, int n_in,
                              void* d_out, int out_size, void* d_ws, size_t ws_size,
                              hipStream_t stream) {
    const float* x   = (const float*)d_in[0];
    const float* W1  = (const float*)d_in[1];
    const float* b1  = (const float*)d_in[2];
    const float* W2  = (const float*)d_in[3];
    const float* b2  = (const float*)d_in[4];
    const float* Wl1 = (const float*)d_in[5];
    const float* bl1 = (const float*)d_in[6];
    const float* Wl2 = (const float*)d_in[7];
    const float* bl2 = (const float*)d_in[8];
    float* out = (float*)d_out;

    char* ws = (char*)d_ws;
    bf16*  w2r    = (bf16*)ws;                                   // 36,864 B
    bf16*  w1f    = (bf16*)(ws + 40960);                         //  1,024 B
    bf16*  wl1t   = (bf16*)(ws + 65536);                         // 3,211,264 B
    bf16*  pooled = (bf16*)(ws + 65536 + 4194304);               // 102,760,448 B
    float* part   = (float*)(ws + 65536 + 4194304 + 102760448);  // 16,777,216 B

    prep_w2   <<<74,             256, 0, stream>>>(W2, w2r, W1, w1f);
    prep_wl1t <<<dim3(196, 2),   256, 0, stream>>>(Wl1, wl1t);
    conv_fused<<<8192,           256, 0, stream>>>(x, b1, w2r, w1f, b2, pooled);
    fc1       <<<dim3(128, 8),   256, 0, stream>>>(pooled, wl1t, part);
    fc2_lsm   <<<1024,           256, 0, stream>>>(part, bl1, Wl2, bl2, out);
}

// Round 10
// 262.952 us; speedup vs baseline: 2.1366x; 1.0609x over previous
//
#include <hip/hip_runtime.h>
#include <math.h>

typedef __bf16 bf16;
typedef __bf16 bf16x8 __attribute__((ext_vector_type(8)));
typedef float f32x4 __attribute__((ext_vector_type(4)));
typedef float f32x16 __attribute__((ext_vector_type(16)));
typedef unsigned int u32x4 __attribute__((ext_vector_type(4)));

__device__ __forceinline__ void load_lds16(const void* g, void* l) {
    __builtin_amdgcn_global_load_lds(
        (const __attribute__((address_space(1))) unsigned int*)g,
        (__attribute__((address_space(3))) unsigned int*)l, 16, 0, 0);
}

// ---------------------------------------------------------------------------
// prep_w2: W2 [cout][ci][tap] f32 -> B-frag buffer for mfma_32x32x16 (conv2),
// PLUS W1 [32][9] f32 -> B-frag buffer w1f for conv1 (K=16, taps 9..15 = 0).
// ---------------------------------------------------------------------------
__global__ void prep_w2(const float* __restrict__ W2, bf16* __restrict__ w2r,
                        const float* __restrict__ W1, bf16* __restrict__ w1f) {
    int e = blockIdx.x * 256 + threadIdx.x;
    if (e < 18432) {
        int j  = e & 7;
        int l  = (e >> 3) & 63;
        int f  = e >> 9;
        int s  = f >> 1;
        int nt = f & 1;
        int tap  = s >> 1;
        int ci   = (s & 1) * 16 + (l >> 5) * 8 + j;
        int cout = nt * 32 + (l & 31);
        w2r[e] = (bf16)W2[cout * 288 + ci * 9 + tap];
    } else {
        int e2 = e - 18432;
        if (e2 < 512) {
            int j = e2 & 7;
            int l = e2 >> 3;
            int k = (l >> 5) * 8 + j;       // tap index (K)
            int n = l & 31;                 // cout
            w1f[e2] = (k < 9) ? (bf16)W1[n * 9 + k] : (bf16)0.f;
        }
    }
}

// ---------------------------------------------------------------------------
// prep_wl1t: Wl1 f32 [12544][128] -> bf16 [128][12544] with permuted K:
// wl1t[n][k'] where k' = site*64 + cout  <->  Wl1 row k = cout*196 + site.
// ---------------------------------------------------------------------------
__global__ void prep_wl1t(const float* __restrict__ Wl1, bf16* __restrict__ wl1t) {
    __shared__ float tile[32 * 129];
    const int t  = threadIdx.x;
    const int s  = blockIdx.x;      // site 0..195
    const int cg = blockIdx.y;      // cout half
    for (int e = t; e < 4096; e += 256) {
        int cl = e >> 7, n = e & 127;
        tile[cl * 129 + n] = Wl1[((long)(cg * 32 + cl) * 196 + s) * 128 + n];
    }
    __syncthreads();
    for (int e = t; e < 4096; e += 256) {
        int n = e >> 5, cl = e & 31;
        wl1t[(long)n * 12544 + s * 64 + cg * 32 + cl] = (bf16)tile[cl * 129 + n];
    }
}

// ---------------------------------------------------------------------------
// conv_fused: BOTH convs on the MFMA pipe. (FROZEN — R9 passing version.)
//  phase1: im2col x -> Aim[480 pos][16 taps] bf16 + masks mrow/mneg (f32)
//          !! every LDS fill > 256 elements MUST be a strided loop — R8's
//          `if (t < 392)` left mneg[256..391] poisoned (0xAA) -> absmax 1.6.
//  phase2: conv1 = MFMA 32x32x16 (M=480 pos, N=32 cout, K=16) + mask/relu
//  phase3: conv2 = MFMA 32x32x16 per Mt, epilogue = mneg-add + max + relu
// __launch_bounds__(256,3) REQUIRED: (256,4) spills breg (R3, R6: 1.3 GB
// scratch). DO NOT raise to 4.
// ---------------------------------------------------------------------------
__global__ __launch_bounds__(256, 3)
void conv_fused(const float* __restrict__ x, const float* __restrict__ b1,
                const bf16* __restrict__ w2r, const bf16* __restrict__ w1f,
                const float* __restrict__ b2, bf16* __restrict__ pooled)
{
    __shared__ __attribute__((aligned(16))) bf16  h1s[16 * 30 * 32];  // 30720 B
    __shared__ __attribute__((aligned(16))) bf16  Aim[480 * 16];      // 15360 B
    __shared__ __attribute__((aligned(16))) float xs[18 * 32];        //  2304 B
    __shared__ __attribute__((aligned(16))) float mrow[480];          //  1920 B
    __shared__ __attribute__((aligned(16))) float mneg[98 * 4];       //  1568 B

    const int t    = threadIdx.x;
    const int lane = t & 63;
    const int wv   = t >> 6;
    const int img  = blockIdx.x >> 1;
    const int hb   = blockIdx.x & 1;        // image half
    const int nt   = wv & 1;                // conv2 cout half
    const int wp   = wv >> 1;               // conv2 Mt parity
    const int ml31 = lane & 31;
    const int lg   = lane >> 5;

    const float* xi = x + img * 784;

    bf16x8 breg[18];
    {
        const bf16x8* wp2 = (const bf16x8*)w2r;
        #pragma unroll
        for (int s = 0; s < 18; s++)
            breg[s] = wp2[(2 * s + nt) * 64 + lane];
    }
    const bf16x8 w1frag = *(const bf16x8*)&w1f[lane * 8];
    const float  b1r    = b1[ml31];
    const float  bias2  = b2[nt * 32 + ml31];

    for (int e = t; e < 18 * 32; e += 256) {
        int j  = e >> 5;
        int c  = e & 31;
        int xr = hb * 14 - 2 + j;
        int xc = c - 1;
        float v = 0.f;
        if (xr >= 0 && xr < 28 && xc >= 0 && xc < 28) v = xi[xr * 28 + xc];
        xs[e] = v;
    }
    __syncthreads();

    // ---- phase 1: im2col + masks
    #pragma unroll
    for (int pp = 0; pp < 2; pp++) {
        int p = t + pp * 256;
        if (p < 480) {
            int r = p / 30, c = p - r * 30;
            const float* xb = &xs[r * 32 + c - 1];
            float v0 = xb[0],  v1 = xb[1],  v2 = xb[2];
            float v3 = xb[32], v4 = xb[33], v5 = xb[34];
            float v6 = xb[64], v7 = xb[65], v8 = xb[66];
            bf16x8 t0;
            t0[0] = (bf16)v0; t0[1] = (bf16)v1; t0[2] = (bf16)v2;
            t0[3] = (bf16)v3; t0[4] = (bf16)v4; t0[5] = (bf16)v5;
            t0[6] = (bf16)v6; t0[7] = (bf16)v7;
            bf16x8 t1;
            #pragma unroll
            for (int j = 0; j < 8; j++) t1[j] = (bf16)0.f;
            t1[0] = (bf16)v8;
            *(bf16x8*)&Aim[p * 16]     = t0;
            *(bf16x8*)&Aim[p * 16 + 8] = t1;
            mrow[p] = (c >= 1 && c <= 28 && v4 != 0.f) ? 1.f : 0.f;
        }
    }
    // mneg: 392 entries > 256 threads -> MUST be a strided loop (R8 bug)
    for (int e = t; e < 392; e += 256) {
        int s   = e >> 2, q = e & 3;
        int spi = s / 14, spj = s - spi * 14;
        float cv = xs[(2 * spi + (q >> 1) + 2) * 32 + 2 * spj + (q & 1) + 1];
        mneg[e] = (cv != 0.f) ? 0.f : -1e30f;
    }
    __syncthreads();

    // ---- phase 2: conv1 via MFMA 32x32x16
    for (int Mt = wv; Mt < 15; Mt += 4) {
        int m = Mt * 32 + ml31;
        bf16x8 af = *(const bf16x8*)&Aim[m * 16 + lg * 8];
        f32x16 acc;
        #pragma unroll
        for (int e = 0; e < 16; e++) acc[e] = b1r;
        acc = __builtin_amdgcn_mfma_f32_32x32x16_bf16(af, w1frag, acc, 0, 0, 0);
        #pragma unroll
        for (int run = 0; run < 4; run++) {
            int p0 = Mt * 32 + run * 8 + 4 * lg;
            f32x4 mk = *(const f32x4*)&mrow[p0];
            #pragma unroll
            for (int j = 0; j < 4; j++) {
                float s = acc[run * 4 + j];
                float o = (mk[j] != 0.f) ? fmaxf(s, 0.f) : 0.f;
                int p = p0 + j;
                h1s[(p * 32 + ml31) ^ ((p & 6) << 2)] = (bf16)o;
            }
        }
    }
    __syncthreads();

    // ---- phase 3: conv2 Mt loop
    const int half = lg;
    const int cib  = half * 8;

    int q  = ml31 & 3;
    int pj = wp * 8 + (ml31 >> 2);
    int pi = 0;
    if (pj >= 14) { pj -= 14; pi = 1; }

    bf16* pout = pooled + (long)img * 12544 + hb * 98 * 64 + nt * 32 + ml31;

    for (int Mt = wp; Mt < 13; Mt += 2) {
        int row = 2 * pi + (q >> 1);
        if (row > 13) row = 13;
        int pb = row * 30 + 2 * pj + (q & 1);

        f32x16 accA, accB = {};
        #pragma unroll
        for (int e = 0; e < 16; e++) accA[e] = bias2;

        int p0  = pb;
        int sw0 = (p0 & 6) << 2;
        bf16x8 a0 = *(const bf16x8*)&h1s[((p0 * 32 + cib) ^ sw0)];
        bf16x8 a1 = *(const bf16x8*)&h1s[((p0 * 32 + 16 + cib) ^ sw0)];
        #pragma unroll
        for (int kt = 0; kt < 9; kt++) {
            bf16x8 na0, na1;
            if (kt < 8) {
                const int dp = ((kt + 1) / 3) * 30 + ((kt + 1) % 3);
                int p  = pb + dp;
                int sw = (p & 6) << 2;
                na0 = *(const bf16x8*)&h1s[((p * 32 + cib) ^ sw)];
                na1 = *(const bf16x8*)&h1s[((p * 32 + 16 + cib) ^ sw)];
            }
            accA = __builtin_amdgcn_mfma_f32_32x32x16_bf16(a0, breg[2 * kt],     accA, 0, 0, 0);
            accB = __builtin_amdgcn_mfma_f32_32x32x16_bf16(a1, breg[2 * kt + 1], accB, 0, 0, 0);
            a0 = na0; a1 = na1;
        }

        int slg = 8 * Mt + half;
        #pragma unroll
        for (int gg = 0; gg < 4; gg++) {
            if (slg < 98) {
                f32x4 mn = *(const f32x4*)&mneg[slg * 4];
                float v0 = accA[gg * 4 + 0] + accB[gg * 4 + 0] + mn[0];
                float v1 = accA[gg * 4 + 1] + accB[gg * 4 + 1] + mn[1];
                float v2 = accA[gg * 4 + 2] + accB[gg * 4 + 2] + mn[2];
                float v3 = accA[gg * 4 + 3] + accB[gg * 4 + 3] + mn[3];
                float pm = fmaxf(fmaxf(v0, v1), fmaxf(v2, v3));
                pout[slg * 64] = (bf16)fmaxf(pm, 0.f);
            }
            slg += 2;
        }

        pj += 2; if (pj >= 14) { pj -= 14; pi += 1; }
        pi += 1;
    }
}

// ---------------------------------------------------------------------------
// fc1: bf16 MFMA split-K GEMM, BK=64 double-buffered global_load_lds.
// ks=7 slices of 1792 k (=28 x 64, NO tail). part[ks][m][n], grid (128,7).
// Buffers: A 32x64 (2 stacked 32x32 subtiles, each with the proven
// element swizzle ^((row&6)<<2)), B 128x64 (2 stacked 128x32 subtiles).
// Chunk c (16B): within subtile, row=(c>>2), src k-quarter=(c&3)^((row>>1)&3).
// LDS 40 KB -> 4 blocks/CU; 28 iters, 8 MFMA/wave/iter.
// ---------------------------------------------------------------------------
__global__ __launch_bounds__(256, 4)
void fc1(const bf16* __restrict__ pooled, const bf16* __restrict__ wl1t,
         float* __restrict__ part)
{
    __shared__ __attribute__((aligned(16))) bf16 As[2][32 * 64];
    __shared__ __attribute__((aligned(16))) bf16 Bs[2][128 * 64];

    const int t    = threadIdx.x;
    const int lane = t & 63;
    const int wv   = t >> 6;
    const int ml   = lane & 15;
    const int kg   = lane >> 4;
    const int wm   = wv & 1;
    const int wn   = wv >> 1;
    const int m0   = blockIdx.x * 32;
    const int ks   = blockIdx.y;
    const int k0   = ks * 1792;

    // A staging: 256 chunks, 1/thread. c=t: sub=(c>>7), i=c&127, r=i>>2,
    // jq=(i&3)^((r>>1)&3); src = pooled[m0+r][k0 + sub*32 + jq*8]
    const bf16* asrc;
    {
        int c  = t;
        int sub = c >> 7, i = c & 127;
        int r  = i >> 2;
        int jq = (i & 3) ^ ((r >> 1) & 3);
        asrc = pooled + (long)(m0 + r) * 12544 + k0 + sub * 32 + jq * 8;
    }
    bf16* adst0 = &As[0][wv * 512];     // wave-uniform (chunks wv*64..+63 -> el wv*512)
    bf16* adst1 = &As[1][wv * 512];

    // B staging: 1024 chunks, 4/thread (u). c=u*256+t: sub=c>>9, i=c&511,
    // r=i>>2 (n-row), jq=(i&3)^((r>>1)&3); src = wl1t[r][k0 + sub*32 + jq*8]
    const bf16* bsrc[4];
    int bbase[4];
    #pragma unroll
    for (int u = 0; u < 4; u++) {
        int c  = u * 256 + t;
        int sub = c >> 9, i = c & 511;
        int r  = i >> 2;
        int jq = (i & 3) ^ ((r >> 1) & 3);
        bsrc[u]  = wl1t + (long)r * 12544 + k0 + sub * 32 + jq * 8;
        bbase[u] = (u * 256 + wv * 64) * 8;     // wave-uniform element base
    }

    // fragment offsets
    const int am = wm * 16 + ml;
    int aoff[2], boff[4];
    #pragma unroll
    for (int s = 0; s < 2; s++)
        aoff[s] = s * 1024 + ((am * 32 + kg * 8) ^ ((am & 6) << 2));
    #pragma unroll
    for (int j = 0; j < 4; j++) {
        int n = wn * 64 + j * 16 + ml;
        boff[j] = (n * 32 + kg * 8) ^ ((n & 6) << 2);
    }

    f32x4 acc[4];
    {
        f32x4 z = {0.f, 0.f, 0.f, 0.f};
        #pragma unroll
        for (int j = 0; j < 4; j++) acc[j] = z;
    }

    // prologue: stage kt=0 into buf 0
    load_lds16(asrc, adst0);
    #pragma unroll
    for (int u = 0; u < 4; u++) load_lds16(bsrc[u], &Bs[0][bbase[u]]);

    for (int kt = 0; kt < 28; kt++) {
        __syncthreads();                        // buf[cur] staged; buf[nxt] free
        const int cur = kt & 1;
        if (kt < 27) {                          // prefetch next (overlaps MFMA)
            const int kb = (kt + 1) * 64;
            load_lds16(asrc + kb, cur ? adst0 : adst1);
            #pragma unroll
            for (int u = 0; u < 4; u++)
                load_lds16(bsrc[u] + kb, &Bs[cur ^ 1][bbase[u]]);
        }
        #pragma unroll
        for (int s = 0; s < 2; s++) {
            bf16x8 af = *(const bf16x8*)&As[cur][aoff[s]];
            #pragma unroll
            for (int j = 0; j < 4; j++) {
                bf16x8 bf = *(const bf16x8*)&Bs[cur][s * 4096 + boff[j]];
                acc[j] = __builtin_amdgcn_mfma_f32_16x16x32_bf16(af, bf, acc[j], 0, 0, 0);
            }
        }
    }

    float* pp = part + ((long)ks * 4096 + m0 + wm * 16) * 128 + wn * 64;
    #pragma unroll
    for (int j = 0; j < 4; j++)
        #pragma unroll
        for (int r = 0; r < 4; r++)
            pp[(kg * 4 + r) * 128 + j * 16 + ml] = acc[j][r];
}

// ---------------------------------------------------------------------------
// fc2_lsm: one wave per image; 7-way split-K reduce + FC2 + log_softmax.
// ---------------------------------------------------------------------------
__global__ __launch_bounds__(256)
void fc2_lsm(const float* __restrict__ part, const float* __restrict__ bl1,
             const float* __restrict__ Wl2, const float* __restrict__ bl2,
             float* __restrict__ out)
{
    const int wv   = threadIdx.x >> 6;
    const int lane = threadIdx.x & 63;
    const int img  = blockIdx.x * 4 + wv;
    const float* pb = part + (long)img * 128;

    float ac[10];
    #pragma unroll
    for (int c = 0; c < 10; c++) ac[c] = 0.f;

    #pragma unroll
    for (int u = 0; u < 2; u++) {
        int n = lane + 64 * u;
        float s = bl1[n];
        #pragma unroll
        for (int k = 0; k < 7; k++) s += pb[(long)k * 4096 * 128 + n];
        float h = s > 0.f ? s : 0.f;
        #pragma unroll
        for (int c = 0; c < 10; c++) ac[c] += h * Wl2[n * 10 + c];
    }
    #pragma unroll
    for (int o = 32; o > 0; o >>= 1)
        #pragma unroll
        for (int c = 0; c < 10; c++) ac[c] += __shfl_down(ac[c], o, 64);

    if (lane == 0) {
        float lg[10], mx = -1e30f;
        #pragma unroll
        for (int c = 0; c < 10; c++) {
            lg[c] = ac[c] + bl2[c];
            mx = lg[c] > mx ? lg[c] : mx;
        }
        float se = 0.f;
        #pragma unroll
        for (int c = 0; c < 10; c++) se += __expf(lg[c] - mx);
        float ls = __logf(se);
        #pragma unroll
        for (int c = 0; c < 10; c++) out[img * 10 + c] = lg[c] - mx - ls;
    }
}

// ---------------------------------------------------------------------------
extern "C" void kernel_launch(void* const* d_in, const int* in_sizes, int n_in,
                              void* d_out, int out_size, void* d_ws, size_t ws_size,
                              hipStream_t stream) {
    const float* x   = (const float*)d_in[0];
    const float* W1  = (const float*)d_in[1];
    const float* b1  = (const float*)d_in[2];
    const float* W2  = (const float*)d_in[3];
    const float* b2  = (const float*)d_in[4];
    const float* Wl1 = (const float*)d_in[5];
    const float* bl1 = (const float*)d_in[6];
    const float* Wl2 = (const float*)d_in[7];
    const float* bl2 = (const float*)d_in[8];
    float* out = (float*)d_out;

    char* ws = (char*)d_ws;
    bf16*  w2r    = (bf16*)ws;                                   // 36,864 B
    bf16*  w1f    = (bf16*)(ws + 40960);                         //  1,024 B
    bf16*  wl1t   = (bf16*)(ws + 65536);                         // 3,211,264 B
    bf16*  pooled = (bf16*)(ws + 65536 + 4194304);               // 102,760,448 B
    float* part   = (float*)(ws + 65536 + 4194304 + 102760448);  // 14,680,064 B

    prep_w2   <<<74,             256, 0, stream>>>(W2, w2r, W1, w1f);
    prep_wl1t <<<dim3(196, 2),   256, 0, stream>>>(Wl1, wl1t);
    conv_fused<<<8192,           256, 0, stream>>>(x, b1, w2r, w1f, b2, pooled);
    fc1       <<<dim3(128, 7),   256, 0, stream>>>(pooled, wl1t, part);
    fc2_lsm   <<<1024,           256, 0, stream>>>(part, bl1, Wl2, bl2, out);
}